// Round 2
// baseline (829.200 us; speedup 1.0000x reference)
//
#include <hip/hip_runtime.h>
#include <hip/hip_bf16.h>

#define LL 2048
#define SS 2048
#define NB 4
#define EE 256
#define HH 8
#define HD 32
#define NH 32           // NB*HH
#define MM (LL*NB)      // 8192

typedef _Float16 f16;
typedef f16 f16x8 __attribute__((ext_vector_type(8)));
typedef float f32x4 __attribute__((ext_vector_type(4)));

__device__ __forceinline__ f16x8 cvt8(float4 a, float4 b) {
  f16x8 r;
  r[0] = (f16)a.x; r[1] = (f16)a.y; r[2] = (f16)a.z; r[3] = (f16)a.w;
  r[4] = (f16)b.x; r[5] = (f16)b.y; r[6] = (f16)b.z; r[7] = (f16)b.w;
  return r;
}

// ---------------------------------------------------------------------------
// Kernel 1: fused QKV projection.
// X (8192 x 256) fp32 @ W^T (256 x 768) -> per-head f16 buffers.
// Q is pre-scaled by HD^-0.5. Layouts: Qh/Kh/Vh[b][pos][d], b = n*8 + h.
// ---------------------------------------------------------------------------
__global__ __launch_bounds__(256) void qkv_proj(
    const float* __restrict__ query, const float* __restrict__ key,
    const float* __restrict__ value, const float* __restrict__ W,
    const float* __restrict__ bias,
    f16* __restrict__ Qh, f16* __restrict__ Kh, f16* __restrict__ Vh)
{
  const int c0 = blockIdx.x * 64;          // [0,768) col tile (one slice each)
  const int m0 = blockIdx.y * 64;          // row tile
  const int w = threadIdx.x >> 6, l = threadIdx.x & 63;
  const int lr = l & 15, lg = l >> 4;
  const int slice = c0 >> 8;               // 0=q,1=k,2=v
  const float* X = (slice == 0) ? query : ((slice == 1) ? key : value);
  const int mrow = m0 + w * 16 + lr;       // A-fragment row

  f32x4 acc[4] = {{0,0,0,0},{0,0,0,0},{0,0,0,0},{0,0,0,0}};
  for (int k0 = 0; k0 < EE; k0 += 32) {
    const float4* ap = (const float4*)(X + (size_t)mrow * EE + k0 + lg * 8);
    f16x8 af = cvt8(ap[0], ap[1]);
#pragma unroll
    for (int f = 0; f < 4; ++f) {
      const float4* bp = (const float4*)(W + (size_t)(c0 + f * 16 + lr) * EE + k0 + lg * 8);
      f16x8 bf = cvt8(bp[0], bp[1]);
      acc[f] = __builtin_amdgcn_mfma_f32_16x16x32_f16(af, bf, acc[f], 0, 0, 0);
    }
  }
  const float scaling = 0.17677669529663687f;  // HD^-0.5
#pragma unroll
  for (int f = 0; f < 4; ++f) {
    const int c = c0 + f * 16 + lr;
    const float bv = bias[c];
    const int cc = c & 255, h = cc >> 5, d = cc & 31;
#pragma unroll
    for (int r = 0; r < 4; ++r) {
      const int m = m0 + w * 16 + lg * 4 + r;   // C row
      const int li = m >> 2, n = m & 3;         // (L,N) flat row -> l, n
      const int bh = n * HH + h;
      const size_t off = (size_t)bh * (LL * HD) + (size_t)li * HD + d;
      const float v = acc[f][r] + bv;
      if (slice == 0)      Qh[off] = (f16)(v * scaling);
      else if (slice == 1) Kh[off] = (f16)v;
      else                 Vh[off] = (f16)v;
    }
  }
}

// ---------------------------------------------------------------------------
// Kernel 2: fused flash attention with additive relative-position bias.
// Grid (L/64, NH). 4 waves/block; each wave owns 16 q-rows independently
// (no __syncthreads). Streams S in 64-wide tiles; rel fp32 is the HBM stream,
// loaded directly in C-fragment lane pattern with 1-tile register prefetch.
// ---------------------------------------------------------------------------
__global__ __launch_bounds__(256) void attn(
    const f16* __restrict__ Qh, const f16* __restrict__ Kh,
    const f16* __restrict__ Vh, const float* __restrict__ rel,
    float* __restrict__ Obuf)
{
  __shared__ f16 P_lds[4][16][72];   // per-wave P tile, padded stride 72 f16
  const int b = blockIdx.y;
  const int q0 = blockIdx.x * 64;
  const int w = threadIdx.x >> 6, l = threadIdx.x & 63;
  const int lr = l & 15, lg = l >> 4;
  const int qw = q0 + w * 16;
  const f16* __restrict__ Qb = Qh + (size_t)b * (LL * HD);
  const f16* __restrict__ Kb = Kh + (size_t)b * (SS * HD);
  const f16* __restrict__ Vb = Vh + (size_t)b * (SS * HD);

  // Q A-fragment: row = lane&15, k(d) = (lane>>4)*8 + j  (16B load, held)
  const f16x8 aq = *(const f16x8*)(Qb + (size_t)(qw + lr) * HD + lg * 8);

  // rel element for (r, f) at tile s0: relbase[r*SS + s0 + f*16]
  const float* relbase = rel + (size_t)b * LL * SS + (size_t)(qw + lg * 4) * SS + lr;

  float m_run[4], s_run[4];
#pragma unroll
  for (int r = 0; r < 4; ++r) { m_run[r] = -1e30f; s_run[r] = 0.f; }
  f32x4 o0 = {0,0,0,0}, o1 = {0,0,0,0};

  float relcur[16], relnxt[16];
#pragma unroll
  for (int r = 0; r < 4; ++r)
#pragma unroll
    for (int f = 0; f < 4; ++f)
      relcur[r * 4 + f] = relbase[(size_t)r * SS + f * 16];

  const float LOG2E = 1.4426950408889634f;
  for (int t = 0; t < SS / 64; ++t) {
    const int s0 = t * 64;
    if (t < SS / 64 - 1) {
#pragma unroll
      for (int r = 0; r < 4; ++r)
#pragma unroll
        for (int f = 0; f < 4; ++f)
          relnxt[r * 4 + f] = relbase[(size_t)r * SS + s0 + 64 + f * 16];
    }
    // QK^T: S tile 16x64, one K=32 mfma per 16-col fragment
    f32x4 sf[4];
#pragma unroll
    for (int f = 0; f < 4; ++f) {
      f16x8 bk = *(const f16x8*)(Kb + (size_t)(s0 + f * 16 + lr) * HD + lg * 8);
      f32x4 z = {0,0,0,0};
      sf[f] = __builtin_amdgcn_mfma_f32_16x16x32_f16(aq, bk, z, 0, 0, 0);
    }
#pragma unroll
    for (int f = 0; f < 4; ++f)
#pragma unroll
      for (int r = 0; r < 4; ++r)
        sf[f][r] += relcur[r * 4 + f];

    // online softmax (fp32); per-row reduce over 16 lanes via shfl_xor
    float p[16];
#pragma unroll
    for (int r = 0; r < 4; ++r) {
      float rm = fmaxf(fmaxf(sf[0][r], sf[1][r]), fmaxf(sf[2][r], sf[3][r]));
      rm = fmaxf(rm, __shfl_xor(rm, 1));
      rm = fmaxf(rm, __shfl_xor(rm, 2));
      rm = fmaxf(rm, __shfl_xor(rm, 4));
      rm = fmaxf(rm, __shfl_xor(rm, 8));
      const float mn = fmaxf(m_run[r], rm);
      float sum = 0.f;
#pragma unroll
      for (int f = 0; f < 4; ++f) {
        const float pv = exp2f((sf[f][r] - mn) * LOG2E);
        p[r * 4 + f] = pv;
        sum += pv;
      }
      sum += __shfl_xor(sum, 1);
      sum += __shfl_xor(sum, 2);
      sum += __shfl_xor(sum, 4);
      sum += __shfl_xor(sum, 8);
      const float sc = exp2f((m_run[r] - mn) * LOG2E);
      s_run[r] = s_run[r] * sc + sum;
      o0[r] *= sc; o1[r] *= sc;
      m_run[r] = mn;
    }

    // P (C-layout) -> LDS [q_local][s_local] f16; wave-private, no barrier
#pragma unroll
    for (int r = 0; r < 4; ++r)
#pragma unroll
      for (int f = 0; f < 4; ++f)
        P_lds[w][lg * 4 + r][f * 16 + lr] = (f16)p[r * 4 + f];

    // PV: O(16x32) += P(16x64) @ V(64x32), two K=32 mfma per d-half
#pragma unroll
    for (int kk = 0; kk < 2; ++kk) {
      f16x8 pa = *(const f16x8*)&P_lds[w][lr][kk * 32 + lg * 8];
#pragma unroll
      for (int df = 0; df < 2; ++df) {
        f16x8 bv;
#pragma unroll
        for (int j = 0; j < 8; ++j)
          bv[j] = Vb[(size_t)(s0 + kk * 32 + lg * 8 + j) * HD + df * 16 + lr];
        if (df == 0) o0 = __builtin_amdgcn_mfma_f32_16x16x32_f16(pa, bv, o0, 0, 0, 0);
        else         o1 = __builtin_amdgcn_mfma_f32_16x16x32_f16(pa, bv, o1, 0, 0, 0);
      }
    }
    if (t < SS / 64 - 1) {
#pragma unroll
      for (int i = 0; i < 16; ++i) relcur[i] = relnxt[i];
    }
  }

  // epilogue: normalize, write Obuf in (L, N, E) layout
  const int n = b >> 3, h = b & 7;
#pragma unroll
  for (int r = 0; r < 4; ++r) {
    const float inv = 1.f / s_run[r];
    const int q = qw + lg * 4 + r;
    float* op = Obuf + (size_t)q * (NB * EE) + n * EE + h * HD;
    op[lr]      = o0[r] * inv;
    op[16 + lr] = o1[r] * inv;
  }
}

// ---------------------------------------------------------------------------
// Kernel 3: output projection (8192x256 @ 256x256^T + bias) -> fp32 out.
// ---------------------------------------------------------------------------
__global__ __launch_bounds__(256) void out_proj(
    const float* __restrict__ Obuf, const float* __restrict__ Wo,
    const float* __restrict__ bo, float* __restrict__ out)
{
  const int c0 = blockIdx.x * 64;
  const int m0 = blockIdx.y * 64;
  const int w = threadIdx.x >> 6, l = threadIdx.x & 63;
  const int lr = l & 15, lg = l >> 4;
  const int mrow = m0 + w * 16 + lr;

  f32x4 acc[4] = {{0,0,0,0},{0,0,0,0},{0,0,0,0},{0,0,0,0}};
  for (int k0 = 0; k0 < EE; k0 += 32) {
    const float4* ap = (const float4*)(Obuf + (size_t)mrow * EE + k0 + lg * 8);
    f16x8 af = cvt8(ap[0], ap[1]);
#pragma unroll
    for (int f = 0; f < 4; ++f) {
      const float4* bp = (const float4*)(Wo + (size_t)(c0 + f * 16 + lr) * EE + k0 + lg * 8);
      f16x8 bf = cvt8(bp[0], bp[1]);
      acc[f] = __builtin_amdgcn_mfma_f32_16x16x32_f16(af, bf, acc[f], 0, 0, 0);
    }
  }
#pragma unroll
  for (int f = 0; f < 4; ++f) {
    const int c = c0 + f * 16 + lr;
    const float bv = bo[c];
#pragma unroll
    for (int r = 0; r < 4; ++r) {
      const int m = m0 + w * 16 + lg * 4 + r;
      out[(size_t)m * EE + c] = acc[f][r] + bv;
    }
  }
}

// ---------------------------------------------------------------------------
extern "C" void kernel_launch(void* const* d_in, const int* in_sizes, int n_in,
                              void* d_out, int out_size, void* d_ws, size_t ws_size,
                              hipStream_t stream) {
  const float* query = (const float*)d_in[0];
  const float* key   = (const float*)d_in[1];
  const float* value = (const float*)d_in[2];
  const float* rel   = (const float*)d_in[3];
  const float* Win   = (const float*)d_in[4];
  const float* bin   = (const float*)d_in[5];
  const float* Wout  = (const float*)d_in[6];
  const float* bout  = (const float*)d_in[7];
  float* out = (float*)d_out;

  char* ws = (char*)d_ws;
  const size_t headbytes = (size_t)NH * LL * HD * sizeof(f16);  // 4 MB
  f16* Qh = (f16*)ws;
  f16* Kh = (f16*)(ws + headbytes);
  f16* Vh = (f16*)(ws + 2 * headbytes);
  float* Obuf = (float*)(ws + 3 * headbytes);                   // 8 MB

  qkv_proj<<<dim3(12, MM / 64), 256, 0, stream>>>(query, key, value, Win, bin, Qh, Kh, Vh);
  attn<<<dim3(LL / 64, NH), 256, 0, stream>>>(Qh, Kh, Vh, rel, Obuf);
  out_proj<<<dim3(EE / 64, MM / 64), 256, 0, stream>>>(Obuf, Wout, bout, out);
}